// Round 9
// baseline (743.637 us; speedup 1.0000x reference)
//
#include <hip/hip_runtime.h>

// ---------------------------------------------------------------------------
// LowFreqSparseAttention: qkv 1x1conv -> l2norm(q,k) -> S=QK^T*scale ->
// top-k(k=N/2) mask -> softmax -> PV -> proj 1x1conv -> GroupNorm(32 groups).
// B=1, C=256, H=W=64 -> N=4096, 8 heads, hd=32, k_sel=2048.
//
// R22 = R19 base (411us attn: best) + MFMA-PV.
// R21 post-mortem: wider RF window flat/worse (419) -> round-count lever
// exhausted. Kernel is issue-bound (VALU 76-78% @ occ 51%) -- the regime
// where offloading PV's ~2800 wave-insts of scalar math to the idle MFMA
// pipe pays (R12's null result was in the stall-bound 21%-occ regime).
//  * QKV GEMM writes V TRANSPOSED as fp16 VT[h][d][n] -- contiguous 8B
//    stores (the old V path was scattered fp32; this avoids R12's GEMM
//    regression). W u8<=255 exact in fp16; V fp16 err ~7e-4 << tol.
//  * phase4 writes fp16 weight row-planes wt2[4][4096] (32KB LDS);
//    exact integer denominators unchanged.
//  * phase5 = v_mfma_f32_16x16x16_f16: A=W (rows 0-3 live), B=VT d-tiles,
//    K = wave's 1024 m in 64 steps; layouts A[l&15][(l>>4)*4+j],
//    B[(l>>4)*4+j][l&15], C row=(l>>4)*4+j col=l&15.
//  * selection = R19's proven RF window (it<8 && width>65536, cap 40).
// Predict: attn ~310-350, MfmaUtil 3-6%, VALU ~65-70.
// Tripwires: absmax fail = MFMA layout wrong -> revert R19;
//            attn ~420 + MfmaUtil>0 = VALU not binding -> re-profile.
// ---------------------------------------------------------------------------

#define NTOK 4096
#define HD 32
#define NHEADS 8
#define KSEL 2048
#define SCALE 0.17677669529663689f   // 32^-0.5  (folded into l2norm_q)
#define LOG2C 7.73937f               // log2(255 / e^0.1767767)

typedef _Float16 f16x4 __attribute__((ext_vector_type(4)));
typedef float f32x4v __attribute__((ext_vector_type(4)));

// ---- helpers --------------------------------------------------------------

__device__ __forceinline__ unsigned fkey(float f) {
  unsigned b = __float_as_uint(f);
  return (b & 0x80000000u) ? ~b : (b | 0x80000000u);
}
__device__ __forceinline__ float unfkey(unsigned k) {
  unsigned b = (k & 0x80000000u) ? (k ^ 0x80000000u) : ~k;
  return __uint_as_float(b);
}
__device__ __forceinline__ unsigned rfl_u(unsigned x) {  // force SGPR
  return __builtin_amdgcn_readfirstlane(x);
}
// regula-falsi probe in key space, clamped to (klo, khi]
__device__ __forceinline__ unsigned probe_rf(unsigned klo, unsigned khi,
                                             float xlo, float xhi,
                                             int clo, int chi) {
  float t = xlo + (xhi - xlo) * ((float)(clo - KSEL) / (float)(clo - chi));
  unsigned k = fkey(t);
  if (k <= klo) k = klo + 1u;
  if (k > khi) k = khi;
  return k;
}

// ---- kernel 1/4: GEMM  C[M][4096] = A[M][256] * B[256][4096] --------------
// SCATTER: M=768 -> Q [h][n][d], KT [h][d][n] (transposed, fp32),
//          VT [h][d][n] (transposed, FP16 -- contiguous 8B stores).
// else:    M=256 -> plain row-major C0.

template <bool SCATTER>
__global__ __launch_bounds__(256) void gemm_k256(
    const float* __restrict__ A, const float* __restrict__ B,
    float* __restrict__ C0, float* __restrict__ C1, float* __restrict__ C2) {
  __shared__ float Wt[64][17];   // +1 pad: avoid 16-way bank conflict
  __shared__ float Xt[16][64];

  const int tid = threadIdx.x;
  const int tx = tid & 15, ty = tid >> 4;
  const int o0 = blockIdx.y * 64, n0 = blockIdx.x * 64;

  const int wr = tid >> 2, wc = (tid & 3) << 2;   // W-tile 64x16 loader
  const int xr = tid >> 4, xc = (tid & 15) << 2;  // X-tile 16x64 loader

  float4 acc[4];
#pragma unroll
  for (int i = 0; i < 4; ++i) acc[i] = make_float4(0.f, 0.f, 0.f, 0.f);

  for (int k0 = 0; k0 < 256; k0 += 16) {
    float4 wv = *(const float4*)(A + (o0 + wr) * 256 + k0 + wc);
    float4 xv = *(const float4*)(B + (k0 + xr) * 4096 + n0 + xc);
    Wt[wr][wc + 0] = wv.x; Wt[wr][wc + 1] = wv.y;
    Wt[wr][wc + 2] = wv.z; Wt[wr][wc + 3] = wv.w;
    *(float4*)&Xt[xr][xc] = xv;
    __syncthreads();
#pragma unroll
    for (int kk = 0; kk < 16; ++kk) {
      float4 b = *(const float4*)&Xt[kk][tx << 2];
#pragma unroll
      for (int i = 0; i < 4; ++i) {
        float a = Wt[(ty << 2) + i][kk];
        acc[i].x += a * b.x; acc[i].y += a * b.y;
        acc[i].z += a * b.z; acc[i].w += a * b.w;
      }
    }
    __syncthreads();
  }

  if (SCATTER) {
#pragma unroll
    for (int i = 0; i < 4; ++i) {
      int o = o0 + (ty << 2) + i;
      int which = o >> 8, rem = o & 255;
      int h = rem >> 5, d = rem & 31;
      int n = n0 + (tx << 2);
      if (which == 1) {
        // KT[h][d][n..n+3]: contiguous float4
        *(float4*)(C1 + h * (HD * NTOK) + d * NTOK + n) = acc[i];
      } else if (which == 2) {
        // VT[h][d][n..n+3]: fp16, contiguous 8B store
        _Float16* vh = (_Float16*)C2;
        f16x4 hv;
        hv[0] = (_Float16)acc[i].x; hv[1] = (_Float16)acc[i].y;
        hv[2] = (_Float16)acc[i].z; hv[3] = (_Float16)acc[i].w;
        *(f16x4*)(vh + h * (HD * NTOK) + d * NTOK + n) = hv;
      } else {
        // Q[h][n][d]: scattered fp32 (norm'd per row later)
        int base = h * (NTOK * HD) + d;
        C0[base + (n + 0) * HD] = acc[i].x;
        C0[base + (n + 1) * HD] = acc[i].y;
        C0[base + (n + 2) * HD] = acc[i].z;
        C0[base + (n + 3) * HD] = acc[i].w;
      }
    }
  } else {
#pragma unroll
    for (int i = 0; i < 4; ++i) {
      int o = o0 + (ty << 2) + i;
      *(float4*)(C0 + o * 4096 + n0 + (tx << 2)) = acc[i];
    }
  }
}

// ---- kernel 2a: l2norm Q rows [h][n][32], folds SCALE ---------------------

__global__ __launch_bounds__(256) void l2norm_q(float* __restrict__ Q) {
  const int tid = threadIdx.x;
  const int p = blockIdx.x * 8 + (tid >> 5);  // (head*4096+n) row index
  const int d = tid & 31;
  const int idx = p * HD + d;
  float v = Q[idx];
  float ss = v * v;
#pragma unroll
  for (int m = 16; m >= 1; m >>= 1) ss += __shfl_xor(ss, m, 32);
  float nrm = sqrtf(ss);
  Q[idx] = v * SCALE / fmaxf(nrm, 1e-12f);
}

// ---- kernel 2b: l2norm KT columns (norm over d at fixed n) ----------------

__global__ __launch_bounds__(256) void l2norm_kt(float* __restrict__ KT) {
  const int n = blockIdx.x * 256 + threadIdx.x;
  float* P = KT + blockIdx.y * (HD * NTOK) + n;
  float v[HD];
  float ss = 0.f;
#pragma unroll
  for (int d = 0; d < HD; ++d) {
    v[d] = P[d * NTOK];          // coalesced across lanes
    ss += v[d] * v[d];
  }
  float inv = 1.f / fmaxf(sqrtf(ss), 1e-12f);
#pragma unroll
  for (int d = 0; d < HD; ++d) P[d * NTOK] = v[d] * inv;
}

// ---- kernel 3: fused attention (4 rows per block, column-partitioned) -----
// phase2: thread tid owns cols {g*1024 + tid*4 + t}; computes ALL 4 rows.
//         q via per-(dg,dd) ds_read_b32 broadcast; all 4 kv float4 issued
//         together per dd (MLP). Loops unroll-bounded (no LICM explosion).
// phase3: hybrid selection (R19 window: RF while it<8 && width>65536, then
//         ulp bisection). Counts readfirstlane'd -> state SALU/SGPR;
//         per-row done-guards skip converged ballots.
// phase4: fp16 weight row-planes wt2[4][4096] in LDS (b64 per row/4 cols);
//         exact integer denominators, block-reduced.
// phase5: MFMA PV: A=W rows 0-3 (fp16 from LDS), B=VT fp16 (global b64),
//         v_mfma_f32_16x16x16_f16 x2 d-tiles x 64 K-steps per wave.

__global__ __launch_bounds__(256, 5) void attn_kernel(
    const float* __restrict__ Q, const float* __restrict__ KT,
    const _Float16* __restrict__ VT, float* __restrict__ AO) {
  __shared__ __align__(16) _Float16 wt2[4][NTOK];         // 32 KB, [row][m]
  __shared__ float qs[128];
  __shared__ float pvred[4 * 4 * 32];                     // 2 KB [wv][r][d]
  __shared__ unsigned ired[2][4][2];                      // bisection dbuf
  __shared__ unsigned dred[4][4];                         // denom partials

  const int tid = threadIdx.x;
  const int wv = tid >> 6, lane = tid & 63;
  const int head = blockIdx.x & 7;          // head == blockIdx%8 -> XCD-pinned
  const int n0 = (blockIdx.x >> 3) << 2;

  const float* Qh = Q + head * (NTOK * HD);
  const float* KTh = KT + head * (HD * NTOK);
  const _Float16* VTh = VT + head * (HD * NTOK);

  // phase 1: stage the block's 4 q rows (already *SCALE from l2norm_q)
  if (tid < 128) qs[tid] = Qh[n0 * HD + tid];
  __syncthreads();

  // phase 2: kr[r][g*4+t] = score(row r, col g*1024 + tid*4 + t).
  // Each K element is read by exactly ONE thread of the block. Per (dg,dd):
  // 4 scalar q broadcasts (ds_read_b32) + 4 kv float4 issued together.
  float kr[4][16];
#pragma unroll
  for (int r = 0; r < 4; ++r)
#pragma unroll
    for (int j = 0; j < 16; ++j) kr[r][j] = 0.f;

  const int cb = tid << 2;
  const float* kbase = KTh + cb;
#define QK8(r, q, a, b, j0)                                                  \
  kr[r][(j0) + 0] += (q) * (a).x; kr[r][(j0) + 1] += (q) * (a).y;            \
  kr[r][(j0) + 2] += (q) * (a).z; kr[r][(j0) + 3] += (q) * (a).w;            \
  kr[r][(j0) + 4] += (q) * (b).x; kr[r][(j0) + 5] += (q) * (b).y;            \
  kr[r][(j0) + 6] += (q) * (b).z; kr[r][(j0) + 7] += (q) * (b).w;
#pragma unroll 1
  for (int dg = 0; dg < 8; ++dg) {
#pragma unroll 1
    for (int dd = 0; dd < 4; ++dd) {
      const int d = (dg << 2) + dd;
      const float* kp = kbase + d * NTOK;
      // all 4 global loads issued before any use (MLP)
      const float4 a0 = *(const float4*)(kp);
      const float4 b0 = *(const float4*)(kp + 1024);
      const float4 a1 = *(const float4*)(kp + 2048);
      const float4 b1 = *(const float4*)(kp + 3072);
      const float q0 = qs[d];            // ds_read_b32 broadcast
      const float q1 = qs[HD + d];
      const float q2 = qs[2 * HD + d];
      const float q3 = qs[3 * HD + d];
      QK8(0, q0, a0, b0, 0) QK8(1, q1, a0, b0, 0)
      QK8(2, q2, a0, b0, 0) QK8(3, q3, a0, b0, 0)
      QK8(0, q0, a1, b1, 8) QK8(1, q1, a1, b1, 8)
      QK8(2, q2, a1, b1, 8) QK8(3, q3, a1, b1, 8)
    }
  }
#undef QK8

  // phase 3: hybrid selection per row (R19 schedule). Bracket invariant
  // (key space): count(klo) >= KSEL, answer in [klo, khi]. RF probe while
  // it<8 && width>65536; ulp midpoint after. Exit on count==KSEL (kept set
  // == reference's top-k; ties make the count skip KSEL so ==KSEL is
  // tie-free) or klo==khi (exact kth key).
  // |scores| <= 0.1768 < 0.25, so anchors (-0.25 -> 4096, +0.25 -> 0).
  // State block-uniform; counts readfirstlane'd -> SGPR/SALU resident.
  unsigned klo0 = 0x417FFFFFu, khi0 = 0xBE800000u;  // fkey(-.25), fkey(.25)
  unsigned klo1 = 0x417FFFFFu, khi1 = 0xBE800000u;
  unsigned klo2 = 0x417FFFFFu, khi2 = 0xBE800000u;
  unsigned klo3 = 0x417FFFFFu, khi3 = 0xBE800000u;
  float xlo0 = -0.25f, xhi0 = 0.25f, xlo1 = -0.25f, xhi1 = 0.25f;
  float xlo2 = -0.25f, xhi2 = 0.25f, xlo3 = -0.25f, xhi3 = 0.25f;
  int clo0 = NTOK, chi0 = 0, clo1 = NTOK, chi1 = 0;
  int clo2 = NTOK, chi2 = 0, clo3 = NTOK, chi3 = 0;
  bool dn0 = false, dn1 = false, dn2 = false, dn3 = false;
  int slot = 0;
#pragma unroll 1
  for (int it = 0; it < 40; ++it) {
    unsigned m0 = dn0 ? klo0
        : ((it < 8 && (khi0 - klo0) > 65536u)
               ? rfl_u(probe_rf(klo0, khi0, xlo0, xhi0, clo0, chi0))
               : klo0 + ((khi0 - klo0 + 1u) >> 1));
    unsigned m1 = dn1 ? klo1
        : ((it < 8 && (khi1 - klo1) > 65536u)
               ? rfl_u(probe_rf(klo1, khi1, xlo1, xhi1, clo1, chi1))
               : klo1 + ((khi1 - klo1 + 1u) >> 1));
    unsigned m2 = dn2 ? klo2
        : ((it < 8 && (khi2 - klo2) > 65536u)
               ? rfl_u(probe_rf(klo2, khi2, xlo2, xhi2, clo2, chi2))
               : klo2 + ((khi2 - klo2 + 1u) >> 1));
    unsigned m3 = dn3 ? klo3
        : ((it < 8 && (khi3 - klo3) > 65536u)
               ? rfl_u(probe_rf(klo3, khi3, xlo3, xhi3, clo3, chi3))
               : klo3 + ((khi3 - klo3 + 1u) >> 1));
    unsigned c0 = 0, c1 = 0, c2 = 0, c3 = 0;
    if (!dn0) {
      const float f0 = unfkey(m0);
#pragma unroll
      for (int j = 0; j < 16; ++j) c0 += __popcll(__ballot(kr[0][j] >= f0));
    }
    if (!dn1) {
      const float f1 = unfkey(m1);
#pragma unroll
      for (int j = 0; j < 16; ++j) c1 += __popcll(__ballot(kr[1][j] >= f1));
    }
    if (!dn2) {
      const float f2 = unfkey(m2);
#pragma unroll
      for (int j = 0; j < 16; ++j) c2 += __popcll(__ballot(kr[2][j] >= f2));
    }
    if (!dn3) {
      const float f3 = unfkey(m3);
#pragma unroll
      for (int j = 0; j < 16; ++j) c3 += __popcll(__ballot(kr[3][j] >= f3));
    }
    if (lane == 0) {
      ired[slot][wv][0] = c0 | (c1 << 16);
      ired[slot][wv][1] = c2 | (c3 << 16);
    }
    __syncthreads();
    unsigned a01 = rfl_u(ired[slot][0][0] + ired[slot][1][0] +
                         ired[slot][2][0] + ired[slot][3][0]);
    unsigned a23 = rfl_u(ired[slot][0][1] + ired[slot][1][1] +
                         ired[slot][2][1] + ired[slot][3][1]);
    slot ^= 1;
    int C0 = (int)(a01 & 0xFFFFu), C1 = (int)(a01 >> 16);
    int C2 = (int)(a23 & 0xFFFFu), C3 = (int)(a23 >> 16);
#define BUPD(C, klo, khi, xlo, xhi, clo, chi, dn, mk)                        \
    if (!dn) {                                                               \
      if (C == KSEL) { klo = mk; dn = true; }                                \
      else if (C > KSEL) { klo = mk; xlo = unfkey(mk); clo = C; }            \
      else { khi = mk - 1u; xhi = unfkey(mk); chi = C; }                     \
      if (klo >= khi) dn = true;                                             \
    }
    BUPD(C0, klo0, khi0, xlo0, xhi0, clo0, chi0, dn0, m0)
    BUPD(C1, klo1, khi1, xlo1, xhi1, clo1, chi1, dn1, m1)
    BUPD(C2, klo2, khi2, xlo2, xhi2, clo2, chi2, dn2, m2)
    BUPD(C3, klo3, khi3, xlo3, xhi3, clo3, chi3, dn3, m3)
#undef BUPD
    if (dn0 && dn1 && dn2 && dn3) break;   // uniform across block
  }
  const float tf0 = unfkey(klo0), tf1 = unfkey(klo1);
  const float tf2 = unfkey(klo2), tf3 = unfkey(klo3);

  // phase 4: fp16 weights into row-planes wt2[r][m]. u = rint(exp(s) *
  // 255/e^smax) in [179,255] kept, 0 masked; integers <=255 are EXACT in
  // fp16. Per g: one b64 store per row (4 consecutive m = cb..cb+3).
  unsigned id0 = 0, id1 = 0, id2 = 0, id3 = 0;
#pragma unroll
  for (int g = 0; g < 4; ++g) {
    f16x4 w0v, w1v, w2v, w3v;
#pragma unroll
    for (int t = 0; t < 4; ++t) {
      const int j = (g << 2) + t;
      float s0 = kr[0][j], s1 = kr[1][j], s2 = kr[2][j], s3 = kr[3][j];
      float u0 = (s0 >= tf0) ? rintf(exp2f(__builtin_fmaf(s0, 1.44269504f, LOG2C))) : 0.f;
      float u1 = (s1 >= tf1) ? rintf(exp2f(__builtin_fmaf(s1, 1.44269504f, LOG2C))) : 0.f;
      float u2 = (s2 >= tf2) ? rintf(exp2f(__builtin_fmaf(s2, 1.44269504f, LOG2C))) : 0.f;
      float u3 = (s3 >= tf3) ? rintf(exp2f(__builtin_fmaf(s3, 1.44269504f, LOG2C))) : 0.f;
      id0 += (unsigned)u0; id1 += (unsigned)u1;
      id2 += (unsigned)u2; id3 += (unsigned)u3;
      w0v[t] = (_Float16)u0; w1v[t] = (_Float16)u1;
      w2v[t] = (_Float16)u2; w3v[t] = (_Float16)u3;
    }
    const int col = (g << 10) + cb;            // 4 consecutive m, 8B-aligned
    *(f16x4*)&wt2[0][col] = w0v;
    *(f16x4*)&wt2[1][col] = w1v;
    *(f16x4*)&wt2[2][col] = w2v;
    *(f16x4*)&wt2[3][col] = w3v;
  }
  // exact integer denominators: wave-reduce then cross-wave sum
#pragma unroll
  for (int s = 1; s < 64; s <<= 1) {
    id0 += __shfl_xor(id0, s); id1 += __shfl_xor(id1, s);
    id2 += __shfl_xor(id2, s); id3 += __shfl_xor(id3, s);
  }
  if (lane == 0) *(uint4*)&dred[wv][0] = make_uint4(id0, id1, id2, id3);
  __syncthreads();  // wt2 + dred visible to all
  const float dnm0 = (float)(dred[0][0] + dred[1][0] + dred[2][0] + dred[3][0]);
  const float dnm1 = (float)(dred[0][1] + dred[1][1] + dred[2][1] + dred[3][1]);
  const float dnm2 = (float)(dred[0][2] + dred[1][2] + dred[2][2] + dred[3][2]);
  const float dnm3 = (float)(dred[0][3] + dred[1][3] + dred[2][3] + dred[3][3]);

  // phase 5: MFMA PV. out[r][d] = sum_m W[r][m] * VT[d][m], wave wv covers
  // m in [wv*1024, +1024) as 64 K=16 steps. A[l&15][(l>>4)*4+j] (rows 0-3
  // live, others zero), B[(l>>4)*4+j][l&15] = VT[d=l&15][k], two d-tiles.
  // C: row=(l>>4)*4+j, col=l&15 -> lanes 0-15 hold rows 0-3.
  {
    const int arow = lane & 15;       // A row / B,C col
    const int kgrp = lane >> 4;       // k sub-group
    const int koff = kgrp << 2;
    const bool alive = arow < 4;
    const _Float16* vb0 = VTh + arow * NTOK;          // d = arow (tile 0)
    const _Float16* vb1 = VTh + (16 + arow) * NTOK;   // d = 16+arow (tile 1)
    const int mbase = wv << 10;
    f32x4v acc0 = {0.f, 0.f, 0.f, 0.f}, acc1 = {0.f, 0.f, 0.f, 0.f};
#pragma unroll 4
    for (int s = 0; s < 64; ++s) {
      const int k0 = mbase + (s << 4) + koff;
      f16x4 a = {0, 0, 0, 0};
      if (alive) a = *(const f16x4*)&wt2[arow][k0];
      const f16x4 b0 = *(const f16x4*)(vb0 + k0);
      const f16x4 b1 = *(const f16x4*)(vb1 + k0);
      acc0 = __builtin_amdgcn_mfma_f32_16x16x16f16(a, b0, acc0, 0, 0, 0);
      acc1 = __builtin_amdgcn_mfma_f32_16x16x16f16(a, b1, acc1, 0, 0, 0);
    }
    if (kgrp == 0) {   // lanes 0-15: rows j=0..3, col=arow
#pragma unroll
      for (int j = 0; j < 4; ++j) {
        pvred[((wv << 2) + j) * 32 + arow] = acc0[j];
        pvred[((wv << 2) + j) * 32 + 16 + arow] = acc1[j];
      }
    }
  }
  __syncthreads();

  if (tid < 128) {
    const int r = tid >> 5, d = tid & 31;
    float val = 0.f;
#pragma unroll
    for (int w = 0; w < 4; ++w) val += pvred[((w << 2) + r) * 32 + d];
    float dn = (r == 0) ? dnm0 : (r == 1) ? dnm1 : (r == 2) ? dnm2 : dnm3;
    val /= dn;
    AO[(head * HD + d) * NTOK + n0 + r] = val;  // [C][N] for proj GEMM
  }
}

// ---- kernel 5: GroupNorm stats (32 groups of 8 ch x 4096 = 32768 vals) ----

__global__ __launch_bounds__(256) void gn_stats(const float* __restrict__ O,
                                                float* __restrict__ ST) {
  const int g = blockIdx.x, tid = threadIdx.x;
  const float4* p4 = (const float4*)(O + g * 32768);
  float s = 0.f, ss = 0.f;
  for (int i = tid; i < 8192; i += 256) {
    float4 v = p4[i];
    s += (v.x + v.y) + (v.z + v.w);
    ss += (v.x * v.x + v.y * v.y) + (v.z * v.z + v.w * v.w);
  }
#pragma unroll
  for (int m = 1; m < 64; m <<= 1) {
    s += __shfl_xor(s, m);
    ss += __shfl_xor(ss, m);
  }
  __shared__ float rs[4], rss[4];
  if ((tid & 63) == 0) { rs[tid >> 6] = s; rss[tid >> 6] = ss; }
  __syncthreads();
  if (tid == 0) {
    float S = rs[0] + rs[1] + rs[2] + rs[3];
    float SS = rss[0] + rss[1] + rss[2] + rss[3];
    float mean = S * (1.f / 32768.f);
    float var = SS * (1.f / 32768.f) - mean * mean;
    ST[g * 2] = mean;
    ST[g * 2 + 1] = rsqrtf(var + 1e-6f);
  }
}

// ---- kernel 6: GroupNorm apply (in place on d_out) ------------------------
// Indexes FLOAT4s: total 1048576/4 = 262144 -> grid 1024 x 256.

__global__ __launch_bounds__(256) void gn_apply(float* __restrict__ O,
                                                const float* __restrict__ ST,
                                                const float* __restrict__ gamma,
                                                const float* __restrict__ beta) {
  const int i4 = blockIdx.x * 256 + threadIdx.x;  // float4 index
  const int c = i4 >> 10, g = c >> 3;
  const float a = ST[g * 2 + 1] * gamma[c];
  const float b = beta[c] - ST[g * 2] * a;
  float4 v = *(float4*)(O + (i4 << 2));
  v.x = v.x * a + b; v.y = v.y * a + b; v.z = v.z * a + b; v.w = v.w * a + b;
  *(float4*)(O + (i4 << 2)) = v;
}

// ---- launch ---------------------------------------------------------------

extern "C" void kernel_launch(void* const* d_in, const int* in_sizes, int n_in,
                              void* d_out, int out_size, void* d_ws,
                              size_t ws_size, hipStream_t stream) {
  const float* x = (const float*)d_in[0];       // [256][4096]
  const float* w_qkv = (const float*)d_in[1];   // [768][256]
  const float* w_proj = (const float*)d_in[2];  // [256][256]
  const float* gamma = (const float*)d_in[3];   // [256]
  const float* beta = (const float*)d_in[4];    // [256]
  float* out = (float*)d_out;                   // [256][4096]

  float* Q = (float*)d_ws;          // [8][4096][32] fp32
  float* KT = Q + 1048576;          // [8][32][4096] fp32 (transposed)
  float* VTr = KT + 1048576;        // [8][32][4096] FP16 (uses 2MB of 4MB)
  float* AO = VTr + 1048576;        // [256][4096] fp32
  float* ST = AO + 1048576;         // [32][2]

  gemm_k256<true><<<dim3(64, 12), 256, 0, stream>>>(w_qkv, x, Q, KT, VTr);
  l2norm_q<<<4096, 256, 0, stream>>>(Q);
  l2norm_kt<<<dim3(16, 8), 256, 0, stream>>>(KT);
  attn_kernel<<<8192, 256, 0, stream>>>(Q, KT, (const _Float16*)VTr, AO);
  gemm_k256<false><<<dim3(64, 4), 256, 0, stream>>>(w_proj, AO, out, nullptr, nullptr);
  gn_stats<<<32, 256, 0, stream>>>(out, ST);
  gn_apply<<<1024, 256, 0, stream>>>(out, ST, gamma, beta);
}

// Round 11
// 502.609 us; speedup vs baseline: 1.4796x; 1.4796x over previous
//
#include <hip/hip_runtime.h>

// ---------------------------------------------------------------------------
// LowFreqSparseAttention: qkv 1x1conv -> l2norm(q,k) -> S=QK^T*scale ->
// top-k(k=N/2) mask -> softmax -> PV -> proj 1x1conv -> GroupNorm(32 groups).
// B=1, C=256, H=W=64 -> N=4096, 8 heads, hd=32, k_sel=2048.
//
// R24 = R23 with the fp16 vector TYPE fixed (compile error only; theory
// untested and unchanged). clang's __builtin_amdgcn_cvt_pkrtz returns
// __fp16 ext_vector(2) ("V2h"), distinct from _Float16 ext_vector(2);
// __builtin_amdgcn_fdot2 takes V2h too. So f16x2 = __fp16-vector and the
// LDS weight planes are __fp16.
//
// R23 rationale (R22 post-mortem): MFMA-PV regressed on FEEDING (16-way
// LDS bank conflicts 786K->12.6M + uncoalesced 8B@8KB-stride B-reads,
// VALU 30%) but absmax HALVED -> fp16 products + fp32 accumulate are
// numerically validated. dot2-PV gets the same issue-reduction with R11's
// proven coalesced V pattern:
//  * phase4: weights as fp16 m-pairs in wt2[4][4096] LDS (u8 ints exact in
//    fp16; cvt_pkrtz exact on integers). 32KB LDS -> still 4 blocks/CU.
//  * phase5: v_dot2_f32_f16 over m-pairs: per 2-m iter = 2 coalesced
//    float4 V loads + 4 cvt_pkrtz + 4 broadcast LDS b32 W-pair reads +
//    16 dot2 (vs 32 fma). ~-40% phase-5 issue. wt2 reads broadcast over
//    8 lanes x 8 consecutive banks = conflict-free.
// Everything else (GEMM, l2norms, phases 1-3, R19 selection window) is
// R19 verbatim.
// Predict: attn ~345-370, VALU ~75 flat, conflicts ~1M, absmax <= 0.0313.
// Falsif.: attn >= 400 -> phase-5 not marginal; next = phase-2 fp16-K dot2.
// ---------------------------------------------------------------------------

#define NTOK 4096
#define HD 32
#define NHEADS 8
#define KSEL 2048
#define SCALE 0.17677669529663689f   // 32^-0.5  (folded into l2norm_q)
#define LOG2C 7.73937f               // log2(255 / e^0.1767767)

typedef __fp16 f16x2 __attribute__((ext_vector_type(2)));

// ---- helpers --------------------------------------------------------------

__device__ __forceinline__ unsigned fkey(float f) {
  unsigned b = __float_as_uint(f);
  return (b & 0x80000000u) ? ~b : (b | 0x80000000u);
}
__device__ __forceinline__ float unfkey(unsigned k) {
  unsigned b = (k & 0x80000000u) ? (k ^ 0x80000000u) : ~k;
  return __uint_as_float(b);
}
__device__ __forceinline__ unsigned rfl_u(unsigned x) {  // force SGPR
  return __builtin_amdgcn_readfirstlane(x);
}
// regula-falsi probe in key space, clamped to (klo, khi]
__device__ __forceinline__ unsigned probe_rf(unsigned klo, unsigned khi,
                                             float xlo, float xhi,
                                             int clo, int chi) {
  float t = xlo + (xhi - xlo) * ((float)(clo - KSEL) / (float)(clo - chi));
  unsigned k = fkey(t);
  if (k <= klo) k = klo + 1u;
  if (k > khi) k = khi;
  return k;
}

// ---- kernel 1/4: GEMM  C[M][4096] = A[M][256] * B[256][4096] --------------
// SCATTER: M=768 -> Q [h][n][d], KT [h][d][n] (transposed!), V [h][n][d].
// else:    M=256 -> plain row-major C0.

template <bool SCATTER>
__global__ __launch_bounds__(256) void gemm_k256(
    const float* __restrict__ A, const float* __restrict__ B,
    float* __restrict__ C0, float* __restrict__ C1, float* __restrict__ C2) {
  __shared__ float Wt[64][17];   // +1 pad: avoid 16-way bank conflict
  __shared__ float Xt[16][64];

  const int tid = threadIdx.x;
  const int tx = tid & 15, ty = tid >> 4;
  const int o0 = blockIdx.y * 64, n0 = blockIdx.x * 64;

  const int wr = tid >> 2, wc = (tid & 3) << 2;   // W-tile 64x16 loader
  const int xr = tid >> 4, xc = (tid & 15) << 2;  // X-tile 16x64 loader

  float4 acc[4];
#pragma unroll
  for (int i = 0; i < 4; ++i) acc[i] = make_float4(0.f, 0.f, 0.f, 0.f);

  for (int k0 = 0; k0 < 256; k0 += 16) {
    float4 wv = *(const float4*)(A + (o0 + wr) * 256 + k0 + wc);
    float4 xv = *(const float4*)(B + (k0 + xr) * 4096 + n0 + xc);
    Wt[wr][wc + 0] = wv.x; Wt[wr][wc + 1] = wv.y;
    Wt[wr][wc + 2] = wv.z; Wt[wr][wc + 3] = wv.w;
    *(float4*)&Xt[xr][xc] = xv;
    __syncthreads();
#pragma unroll
    for (int kk = 0; kk < 16; ++kk) {
      float4 b = *(const float4*)&Xt[kk][tx << 2];
#pragma unroll
      for (int i = 0; i < 4; ++i) {
        float a = Wt[(ty << 2) + i][kk];
        acc[i].x += a * b.x; acc[i].y += a * b.y;
        acc[i].z += a * b.z; acc[i].w += a * b.w;
      }
    }
    __syncthreads();
  }

  if (SCATTER) {
#pragma unroll
    for (int i = 0; i < 4; ++i) {
      int o = o0 + (ty << 2) + i;
      int which = o >> 8, rem = o & 255;
      int h = rem >> 5, d = rem & 31;
      int n = n0 + (tx << 2);
      if (which == 1) {
        // KT[h][d][n..n+3]: contiguous float4
        *(float4*)(C1 + h * (HD * NTOK) + d * NTOK + n) = acc[i];
      } else {
        float* dst = (which == 0) ? C0 : C2;
        int base = h * (NTOK * HD) + d;
        dst[base + (n + 0) * HD] = acc[i].x;
        dst[base + (n + 1) * HD] = acc[i].y;
        dst[base + (n + 2) * HD] = acc[i].z;
        dst[base + (n + 3) * HD] = acc[i].w;
      }
    }
  } else {
#pragma unroll
    for (int i = 0; i < 4; ++i) {
      int o = o0 + (ty << 2) + i;
      *(float4*)(C0 + o * 4096 + n0 + (tx << 2)) = acc[i];
    }
  }
}

// ---- kernel 2a: l2norm Q rows [h][n][32], folds SCALE ---------------------

__global__ __launch_bounds__(256) void l2norm_q(float* __restrict__ Q) {
  const int tid = threadIdx.x;
  const int p = blockIdx.x * 8 + (tid >> 5);  // (head*4096+n) row index
  const int d = tid & 31;
  const int idx = p * HD + d;
  float v = Q[idx];
  float ss = v * v;
#pragma unroll
  for (int m = 16; m >= 1; m >>= 1) ss += __shfl_xor(ss, m, 32);
  float nrm = sqrtf(ss);
  Q[idx] = v * SCALE / fmaxf(nrm, 1e-12f);
}

// ---- kernel 2b: l2norm KT columns (norm over d at fixed n) ----------------

__global__ __launch_bounds__(256) void l2norm_kt(float* __restrict__ KT) {
  const int n = blockIdx.x * 256 + threadIdx.x;
  float* P = KT + blockIdx.y * (HD * NTOK) + n;
  float v[HD];
  float ss = 0.f;
#pragma unroll
  for (int d = 0; d < HD; ++d) {
    v[d] = P[d * NTOK];          // coalesced across lanes
    ss += v[d] * v[d];
  }
  float inv = 1.f / fmaxf(sqrtf(ss), 1e-12f);
#pragma unroll
  for (int d = 0; d < HD; ++d) P[d * NTOK] = v[d] * inv;
}

// ---- kernel 3: fused attention (4 rows per block, column-partitioned) -----
// phase2: thread tid owns cols {g*1024 + tid*4 + t}; computes ALL 4 rows.
//         q via per-(dg,dd) ds_read_b32 broadcast; all 4 kv float4 issued
//         together per dd (MLP). Loops unroll-bounded (no LICM explosion).
// phase3: hybrid selection (R19 window: RF while it<8 && width>65536, then
//         ulp bisection). Counts readfirstlane'd -> state SALU/SGPR;
//         per-row done-guards skip converged ballots.
// phase4: fp16 weight m-pairs into wt2[4][4096] (u8-scale ints, exact);
//         exact integer denominators, block-reduced.
// phase5: PV via v_dot2_f32_f16 over m-pairs (fp32 accumulate), V fp32
//         loads coalesced as in R11, packed with cvt_pkrtz.

__global__ __launch_bounds__(256, 5) void attn_kernel(
    const float* __restrict__ Q, const float* __restrict__ KT,
    const float* __restrict__ V, float* __restrict__ AO) {
  __shared__ __align__(16) __fp16 wt2[4][NTOK];           // 32 KB, [row][m]
  __shared__ float qs[128];
  __shared__ float pvred[4 * 8 * 4 * 4];                  // 2 KB
  __shared__ unsigned ired[2][4][2];                      // bisection dbuf
  __shared__ unsigned dred[4][4];                         // denom partials

  const int tid = threadIdx.x;
  const int wv = tid >> 6, lane = tid & 63;
  const int head = blockIdx.x & 7;          // head == blockIdx%8 -> XCD-pinned
  const int n0 = (blockIdx.x >> 3) << 2;

  const float* Qh = Q + head * (NTOK * HD);
  const float* KTh = KT + head * (HD * NTOK);
  const float* Vh = V + head * (NTOK * HD);

  // phase 1: stage the block's 4 q rows (already *SCALE from l2norm_q)
  if (tid < 128) qs[tid] = Qh[n0 * HD + tid];
  __syncthreads();

  // phase 2: kr[r][g*4+t] = score(row r, col g*1024 + tid*4 + t).
  // Each K element is read by exactly ONE thread of the block. Per (dg,dd):
  // 4 scalar q broadcasts (ds_read_b32) + 4 kv float4 issued together.
  float kr[4][16];
#pragma unroll
  for (int r = 0; r < 4; ++r)
#pragma unroll
    for (int j = 0; j < 16; ++j) kr[r][j] = 0.f;

  const int cb = tid << 2;
  const float* kbase = KTh + cb;
#define QK8(r, q, a, b, j0)                                                  \
  kr[r][(j0) + 0] += (q) * (a).x; kr[r][(j0) + 1] += (q) * (a).y;            \
  kr[r][(j0) + 2] += (q) * (a).z; kr[r][(j0) + 3] += (q) * (a).w;            \
  kr[r][(j0) + 4] += (q) * (b).x; kr[r][(j0) + 5] += (q) * (b).y;            \
  kr[r][(j0) + 6] += (q) * (b).z; kr[r][(j0) + 7] += (q) * (b).w;
#pragma unroll 1
  for (int dg = 0; dg < 8; ++dg) {
#pragma unroll 1
    for (int dd = 0; dd < 4; ++dd) {
      const int d = (dg << 2) + dd;
      const float* kp = kbase + d * NTOK;
      // all 4 global loads issued before any use (MLP)
      const float4 a0 = *(const float4*)(kp);
      const float4 b0 = *(const float4*)(kp + 1024);
      const float4 a1 = *(const float4*)(kp + 2048);
      const float4 b1 = *(const float4*)(kp + 3072);
      const float q0 = qs[d];            // ds_read_b32 broadcast
      const float q1 = qs[HD + d];
      const float q2 = qs[2 * HD + d];
      const float q3 = qs[3 * HD + d];
      QK8(0, q0, a0, b0, 0) QK8(1, q1, a0, b0, 0)
      QK8(2, q2, a0, b0, 0) QK8(3, q3, a0, b0, 0)
      QK8(0, q0, a1, b1, 8) QK8(1, q1, a1, b1, 8)
      QK8(2, q2, a1, b1, 8) QK8(3, q3, a1, b1, 8)
    }
  }
#undef QK8

  // phase 3: hybrid selection per row (R19 schedule). Bracket invariant
  // (key space): count(klo) >= KSEL, answer in [klo, khi]. RF probe while
  // it<8 && width>65536; ulp midpoint after. Exit on count==KSEL (kept set
  // == reference's top-k; ties make the count skip KSEL so ==KSEL is
  // tie-free) or klo==khi (exact kth key).
  // |scores| <= 0.1768 < 0.25, so anchors (-0.25 -> 4096, +0.25 -> 0).
  // State block-uniform; counts readfirstlane'd -> SGPR/SALU resident.
  unsigned klo0 = 0x417FFFFFu, khi0 = 0xBE800000u;  // fkey(-.25), fkey(.25)
  unsigned klo1 = 0x417FFFFFu, khi1 = 0xBE800000u;
  unsigned klo2 = 0x417FFFFFu, khi2 = 0xBE800000u;
  unsigned klo3 = 0x417FFFFFu, khi3 = 0xBE800000u;
  float xlo0 = -0.25f, xhi0 = 0.25f, xlo1 = -0.25f, xhi1 = 0.25f;
  float xlo2 = -0.25f, xhi2 = 0.25f, xlo3 = -0.25f, xhi3 = 0.25f;
  int clo0 = NTOK, chi0 = 0, clo1 = NTOK, chi1 = 0;
  int clo2 = NTOK, chi2 = 0, clo3 = NTOK, chi3 = 0;
  bool dn0 = false, dn1 = false, dn2 = false, dn3 = false;
  int slot = 0;
#pragma unroll 1
  for (int it = 0; it < 40; ++it) {
    unsigned m0 = dn0 ? klo0
        : ((it < 8 && (khi0 - klo0) > 65536u)
               ? rfl_u(probe_rf(klo0, khi0, xlo0, xhi0, clo0, chi0))
               : klo0 + ((khi0 - klo0 + 1u) >> 1));
    unsigned m1 = dn1 ? klo1
        : ((it < 8 && (khi1 - klo1) > 65536u)
               ? rfl_u(probe_rf(klo1, khi1, xlo1, xhi1, clo1, chi1))
               : klo1 + ((khi1 - klo1 + 1u) >> 1));
    unsigned m2 = dn2 ? klo2
        : ((it < 8 && (khi2 - klo2) > 65536u)
               ? rfl_u(probe_rf(klo2, khi2, xlo2, xhi2, clo2, chi2))
               : klo2 + ((khi2 - klo2 + 1u) >> 1));
    unsigned m3 = dn3 ? klo3
        : ((it < 8 && (khi3 - klo3) > 65536u)
               ? rfl_u(probe_rf(klo3, khi3, xlo3, xhi3, clo3, chi3))
               : klo3 + ((khi3 - klo3 + 1u) >> 1));
    unsigned c0 = 0, c1 = 0, c2 = 0, c3 = 0;
    if (!dn0) {
      const float f0 = unfkey(m0);
#pragma unroll
      for (int j = 0; j < 16; ++j) c0 += __popcll(__ballot(kr[0][j] >= f0));
    }
    if (!dn1) {
      const float f1 = unfkey(m1);
#pragma unroll
      for (int j = 0; j < 16; ++j) c1 += __popcll(__ballot(kr[1][j] >= f1));
    }
    if (!dn2) {
      const float f2 = unfkey(m2);
#pragma unroll
      for (int j = 0; j < 16; ++j) c2 += __popcll(__ballot(kr[2][j] >= f2));
    }
    if (!dn3) {
      const float f3 = unfkey(m3);
#pragma unroll
      for (int j = 0; j < 16; ++j) c3 += __popcll(__ballot(kr[3][j] >= f3));
    }
    if (lane == 0) {
      ired[slot][wv][0] = c0 | (c1 << 16);
      ired[slot][wv][1] = c2 | (c3 << 16);
    }
    __syncthreads();
    unsigned a01 = rfl_u(ired[slot][0][0] + ired[slot][1][0] +
                         ired[slot][2][0] + ired[slot][3][0]);
    unsigned a23 = rfl_u(ired[slot][0][1] + ired[slot][1][1] +
                         ired[slot][2][1] + ired[slot][3][1]);
    slot ^= 1;
    int C0 = (int)(a01 & 0xFFFFu), C1 = (int)(a01 >> 16);
    int C2 = (int)(a23 & 0xFFFFu), C3 = (int)(a23 >> 16);
#define BUPD(C, klo, khi, xlo, xhi, clo, chi, dn, mk)                        \
    if (!dn) {                                                               \
      if (C == KSEL) { klo = mk; dn = true; }                                \
      else if (C > KSEL) { klo = mk; xlo = unfkey(mk); clo = C; }            \
      else { khi = mk - 1u; xhi = unfkey(mk); chi = C; }                     \
      if (klo >= khi) dn = true;                                             \
    }
    BUPD(C0, klo0, khi0, xlo0, xhi0, clo0, chi0, dn0, m0)
    BUPD(C1, klo1, khi1, xlo1, xhi1, clo1, chi1, dn1, m1)
    BUPD(C2, klo2, khi2, xlo2, xhi2, clo2, chi2, dn2, m2)
    BUPD(C3, klo3, khi3, xlo3, xhi3, clo3, chi3, dn3, m3)
#undef BUPD
    if (dn0 && dn1 && dn2 && dn3) break;   // uniform across block
  }
  const float tf0 = unfkey(klo0), tf1 = unfkey(klo1);
  const float tf2 = unfkey(klo2), tf3 = unfkey(klo3);

  // phase 4: fp16 weight m-pairs into wt2[r][m]. u = rint(exp(s) *
  // 255/e^smax) in [179,255] kept, 0 masked; integers <=255 are EXACT in
  // fp16 (cvt_pkrtz exact on integers). Thread owns 4 consecutive cols per
  // group -> 2 pair-writes (b32) per row per group.
  unsigned id0 = 0, id1 = 0, id2 = 0, id3 = 0;
#pragma unroll
  for (int g = 0; g < 4; ++g) {
#pragma unroll
    for (int tp = 0; tp < 2; ++tp) {
      const int j0 = (g << 2) + (tp << 1), j1 = j0 + 1;
      float uA0 = (kr[0][j0] >= tf0) ? rintf(exp2f(__builtin_fmaf(kr[0][j0], 1.44269504f, LOG2C))) : 0.f;
      float uB0 = (kr[0][j1] >= tf0) ? rintf(exp2f(__builtin_fmaf(kr[0][j1], 1.44269504f, LOG2C))) : 0.f;
      float uA1 = (kr[1][j0] >= tf1) ? rintf(exp2f(__builtin_fmaf(kr[1][j0], 1.44269504f, LOG2C))) : 0.f;
      float uB1 = (kr[1][j1] >= tf1) ? rintf(exp2f(__builtin_fmaf(kr[1][j1], 1.44269504f, LOG2C))) : 0.f;
      float uA2 = (kr[2][j0] >= tf2) ? rintf(exp2f(__builtin_fmaf(kr[2][j0], 1.44269504f, LOG2C))) : 0.f;
      float uB2 = (kr[2][j1] >= tf2) ? rintf(exp2f(__builtin_fmaf(kr[2][j1], 1.44269504f, LOG2C))) : 0.f;
      float uA3 = (kr[3][j0] >= tf3) ? rintf(exp2f(__builtin_fmaf(kr[3][j0], 1.44269504f, LOG2C))) : 0.f;
      float uB3 = (kr[3][j1] >= tf3) ? rintf(exp2f(__builtin_fmaf(kr[3][j1], 1.44269504f, LOG2C))) : 0.f;
      id0 += (unsigned)uA0 + (unsigned)uB0;
      id1 += (unsigned)uA1 + (unsigned)uB1;
      id2 += (unsigned)uA2 + (unsigned)uB2;
      id3 += (unsigned)uA3 + (unsigned)uB3;
      const int col = (g << 10) + cb + (tp << 1);
      *(f16x2*)&wt2[0][col] = __builtin_amdgcn_cvt_pkrtz(uA0, uB0);
      *(f16x2*)&wt2[1][col] = __builtin_amdgcn_cvt_pkrtz(uA1, uB1);
      *(f16x2*)&wt2[2][col] = __builtin_amdgcn_cvt_pkrtz(uA2, uB2);
      *(f16x2*)&wt2[3][col] = __builtin_amdgcn_cvt_pkrtz(uA3, uB3);
    }
  }
  // exact integer denominators: wave-reduce then cross-wave sum
#pragma unroll
  for (int s = 1; s < 64; s <<= 1) {
    id0 += __shfl_xor(id0, s); id1 += __shfl_xor(id1, s);
    id2 += __shfl_xor(id2, s); id3 += __shfl_xor(id3, s);
  }
  if (lane == 0) *(uint4*)&dred[wv][0] = make_uint4(id0, id1, id2, id3);
  __syncthreads();  // wt2 + dred visible to all
  const float dnm0 = (float)(dred[0][0] + dred[1][0] + dred[2][0] + dred[3][0]);
  const float dnm1 = (float)(dred[0][1] + dred[1][1] + dred[2][1] + dred[3][1]);
  const float dnm2 = (float)(dred[0][2] + dred[1][2] + dred[2][2] + dred[3][2]);
  const float dnm3 = (float)(dred[0][3] + dred[1][3] + dred[2][3] + dred[3][3]);

  // phase 5: PV via dot2 over m-pairs. wave wv covers m in [wv*1024,+1024):
  // iter ii, lane-group mg handles pair (mp, mp+1), mp = mbase+16*ii+2*mg.
  // V loads: two coalesced float4 rows (same traffic as R11). W pairs:
  // broadcast ds_read_b32 (8 lanes/addr, 8 banks) -- conflict-free.
  const int slot5 = lane & 7, mg = lane >> 3;
  const int mbase = wv << 10;
  float av[4][4];
#pragma unroll
  for (int r = 0; r < 4; ++r)
#pragma unroll
    for (int c = 0; c < 4; ++c) av[r][c] = 0.f;

#pragma unroll 4
  for (int ii = 0; ii < 64; ++ii) {
    const int mp = mbase + (ii << 4) + (mg << 1);
    const float4 va = *(const float4*)(Vh + mp * HD + (slot5 << 2));
    const float4 vb = *(const float4*)(Vh + (mp + 1) * HD + (slot5 << 2));
#if __has_builtin(__builtin_amdgcn_fdot2) && __has_builtin(__builtin_amdgcn_cvt_pkrtz)
    const f16x2 vp0 = __builtin_amdgcn_cvt_pkrtz(va.x, vb.x);
    const f16x2 vp1 = __builtin_amdgcn_cvt_pkrtz(va.y, vb.y);
    const f16x2 vp2 = __builtin_amdgcn_cvt_pkrtz(va.z, vb.z);
    const f16x2 vp3 = __builtin_amdgcn_cvt_pkrtz(va.w, vb.w);
    const f16x2 w0 = *(const f16x2*)&wt2[0][mp];
    const f16x2 w1 = *(const f16x2*)&wt2[1][mp];
    const f16x2 w2 = *(const f16x2*)&wt2[2][mp];
    const f16x2 w3 = *(const f16x2*)&wt2[3][mp];
    av[0][0] = __builtin_amdgcn_fdot2(w0, vp0, av[0][0], false);
    av[0][1] = __builtin_amdgcn_fdot2(w0, vp1, av[0][1], false);
    av[0][2] = __builtin_amdgcn_fdot2(w0, vp2, av[0][2], false);
    av[0][3] = __builtin_amdgcn_fdot2(w0, vp3, av[0][3], false);
    av[1][0] = __builtin_amdgcn_fdot2(w1, vp0, av[1][0], false);
    av[1][1] = __builtin_amdgcn_fdot2(w1, vp1, av[1][1], false);
    av[1][2] = __builtin_amdgcn_fdot2(w1, vp2, av[1][2], false);
    av[1][3] = __builtin_amdgcn_fdot2(w1, vp3, av[1][3], false);
    av[2][0] = __builtin_amdgcn_fdot2(w2, vp0, av[2][0], false);
    av[2][1] = __builtin_amdgcn_fdot2(w2, vp1, av[2][1], false);
    av[2][2] = __builtin_amdgcn_fdot2(w2, vp2, av[2][2], false);
    av[2][3] = __builtin_amdgcn_fdot2(w2, vp3, av[2][3], false);
    av[3][0] = __builtin_amdgcn_fdot2(w3, vp0, av[3][0], false);
    av[3][1] = __builtin_amdgcn_fdot2(w3, vp1, av[3][1], false);
    av[3][2] = __builtin_amdgcn_fdot2(w3, vp2, av[3][2], false);
    av[3][3] = __builtin_amdgcn_fdot2(w3, vp3, av[3][3], false);
#else
    const f16x2 w0 = *(const f16x2*)&wt2[0][mp];
    const f16x2 w1 = *(const f16x2*)&wt2[1][mp];
    const f16x2 w2 = *(const f16x2*)&wt2[2][mp];
    const f16x2 w3 = *(const f16x2*)&wt2[3][mp];
    const float w0a = (float)w0[0], w0b = (float)w0[1];
    const float w1a = (float)w1[0], w1b = (float)w1[1];
    const float w2a = (float)w2[0], w2b = (float)w2[1];
    const float w3a = (float)w3[0], w3b = (float)w3[1];
    av[0][0] += w0a * va.x + w0b * vb.x; av[0][1] += w0a * va.y + w0b * vb.y;
    av[0][2] += w0a * va.z + w0b * vb.z; av[0][3] += w0a * va.w + w0b * vb.w;
    av[1][0] += w1a * va.x + w1b * vb.x; av[1][1] += w1a * va.y + w1b * vb.y;
    av[1][2] += w1a * va.z + w1b * vb.z; av[1][3] += w1a * va.w + w1b * vb.w;
    av[2][0] += w2a * va.x + w2b * vb.x; av[2][1] += w2a * va.y + w2b * vb.y;
    av[2][2] += w2a * va.z + w2b * vb.z; av[2][3] += w2a * va.w + w2b * vb.w;
    av[3][0] += w3a * va.x + w3b * vb.x; av[3][1] += w3a * va.y + w3b * vb.y;
    av[3][2] += w3a * va.z + w3b * vb.z; av[3][3] += w3a * va.w + w3b * vb.w;
#endif
  }
  // reduce over mg (lane bits 3..5)
#pragma unroll
  for (int r = 0; r < 4; ++r)
#pragma unroll
    for (int c = 0; c < 4; ++c) {
      float x = av[r][c];
      x += __shfl_xor(x, 8); x += __shfl_xor(x, 16); x += __shfl_xor(x, 32);
      av[r][c] = x;
    }
  if (mg == 0) {
#pragma unroll
    for (int r = 0; r < 4; ++r)
#pragma unroll
      for (int c = 0; c < 4; ++c)
        pvred[(((wv << 3) + slot5) * 4 + r) * 4 + c] = av[r][c];
  }
  __syncthreads();

  if (tid < 128) {
    const int r = tid >> 5, d = tid & 31;
    const int sl = d >> 2, c = d & 3;
    float val = 0.f;
#pragma unroll
    for (int w = 0; w < 4; ++w) val += pvred[(((w << 3) + sl) * 4 + r) * 4 + c];
    float dn = (r == 0) ? dnm0 : (r == 1) ? dnm1 : (r == 2) ? dnm2 : dnm3;
    val /= dn;
    AO[(head * HD + d) * NTOK + n0 + r] = val;  // [C][N] for proj GEMM
  }
}

// ---- kernel 5: GroupNorm stats (32 groups of 8 ch x 4096 = 32768 vals) ----

__global__ __launch_bounds__(256) void gn_stats(const float* __restrict__ O,
                                                float* __restrict__ ST) {
  const int g = blockIdx.x, tid = threadIdx.x;
  const float4* p4 = (const float4*)(O + g * 32768);
  float s = 0.f, ss = 0.f;
  for (int i = tid; i < 8192; i += 256) {
    float4 v = p4[i];
    s += (v.x + v.y) + (v.z + v.w);
    ss += (v.x * v.x + v.y * v.y) + (v.z * v.z + v.w * v.w);
  }
#pragma unroll
  for (int m = 1; m < 64; m <<= 1) {
    s += __shfl_xor(s, m);
    ss += __shfl_xor(ss, m);
  }
  __shared__ float rs[4], rss[4];
  if ((tid & 63) == 0) { rs[tid >> 6] = s; rss[tid >> 6] = ss; }
  __syncthreads();
  if (tid == 0) {
    float S = rs[0] + rs[1] + rs[2] + rs[3];
    float SS = rss[0] + rss[1] + rss[2] + rss[3];
    float mean = S * (1.f / 32768.f);
    float var = SS * (1.f / 32768.f) - mean * mean;
    ST[g * 2] = mean;
    ST[g * 2 + 1] = rsqrtf(var + 1e-6f);
  }
}

// ---- kernel 6: GroupNorm apply (in place on d_out) ------------------------
// Indexes FLOAT4s: total 1048576/4 = 262144 -> grid 1024 x 256.

__global__ __launch_bounds__(256) void gn_apply(float* __restrict__ O,
                                                const float* __restrict__ ST,
                                                const float* __restrict__ gamma,
                                                const float* __restrict__ beta) {
  const int i4 = blockIdx.x * 256 + threadIdx.x;  // float4 index
  const int c = i4 >> 10, g = c >> 3;
  const float a = ST[g * 2 + 1] * gamma[c];
  const float b = beta[c] - ST[g * 2] * a;
  float4 v = *(float4*)(O + (i4 << 2));
  v.x = v.x * a + b; v.y = v.y * a + b; v.z = v.z * a + b; v.w = v.w * a + b;
  *(float4*)(O + (i4 << 2)) = v;
}

// ---- launch ---------------------------------------------------------------

extern "C" void kernel_launch(void* const* d_in, const int* in_sizes, int n_in,
                              void* d_out, int out_size, void* d_ws,
                              size_t ws_size, hipStream_t stream) {
  const float* x = (const float*)d_in[0];       // [256][4096]
  const float* w_qkv = (const float*)d_in[1];   // [768][256]
  const float* w_proj = (const float*)d_in[2];  // [256][256]
  const float* gamma = (const float*)d_in[3];   // [256]
  const float* beta = (const float*)d_in[4];    // [256]
  float* out = (float*)d_out;                   // [256][4096]

  float* Q = (float*)d_ws;          // [8][4096][32]
  float* KT = Q + 1048576;          // [8][32][4096]  (transposed)
  float* V = KT + 1048576;          // [8][4096][32]
  float* AO = V + 1048576;          // [256][4096]
  float* ST = AO + 1048576;         // [32][2]

  gemm_k256<true><<<dim3(64, 12), 256, 0, stream>>>(w_qkv, x, Q, KT, V);
  l2norm_q<<<4096, 256, 0, stream>>>(Q);
  l2norm_kt<<<dim3(16, 8), 256, 0, stream>>>(KT);
  attn_kernel<<<8192, 256, 0, stream>>>(Q, KT, V, AO);
  gemm_k256<false><<<dim3(64, 4), 256, 0, stream>>>(w_proj, AO, out, nullptr, nullptr);
  gn_stats<<<32, 256, 0, stream>>>(out, ST);
  gn_apply<<<1024, 256, 0, stream>>>(out, ST, gamma, beta);
}